// Round 7
// baseline (42.374 us; speedup 1.0000x reference)
//
#include <hip/hip_runtime.h>

// Problem constants (match reference)
constexpr int Bv = 4;
constexpr int Cv = 1024;
constexpr int Hv = 64;
constexpr int Wv = 64;
constexpr int NROIS = 256;
constexpr int HWv = Hv * Wv;   // 4096
constexpr int PIX = Bv * HWv;  // 16384
constexpr int G = 16;          // channel groups (R1-proven config)
constexpr int CPG = Cv / G;    // 64 channels per group

// ---------------------------------------------------------------------------
// k1 (R1-proven, at BW ceiling): thread t -> channel group g = t>>12, float4
// pixel-quad v = t&4095. Per load instruction a wave reads 64*16 B = 1 KB
// CONTIGUOUS (the pattern R5/R6 proved essential: 64B segs = 2.4 TB/s,
// 256B = 3.6 TB/s, 1KB = ~6.4 TB/s effective).
// 256 blocks x 256 threads. Also zeroes out[0] (stream order => before kB).
// ---------------------------------------------------------------------------
__global__ __launch_bounds__(256) void k_diff2_partial(
    const float* __restrict__ std_f, const float* __restrict__ tch_f,
    float* __restrict__ partial, float* __restrict__ out) {
  int t = blockIdx.x * 256 + threadIdx.x;  // [0, 65536)
  if (t == 0) out[0] = 0.f;
  int g = t >> 12;           // channel group [0,16)
  int v = t & 4095;          // float4-unit index over all pixels
  int p = v << 2;            // pixel index, 4 consecutive
  int b = p >> 12;           // batch (HW = 4096)
  int hw = p & 4095;         // pixel within batch

  const float* ps = std_f + ((size_t)b * Cv + (size_t)g * CPG) * HWv + hw;
  const float* pt = tch_f + ((size_t)b * Cv + (size_t)g * CPG) * HWv + hw;

  float4 acc = make_float4(0.f, 0.f, 0.f, 0.f);
#pragma unroll 4
  for (int c = 0; c < CPG; ++c) {
    float4 s = *reinterpret_cast<const float4*>(ps + (size_t)c * HWv);
    float4 q = *reinterpret_cast<const float4*>(pt + (size_t)c * HWv);
    float dx = s.x - q.x, dy = s.y - q.y, dz = s.z - q.z, dw = s.w - q.w;
    acc.x += dx * dx;
    acc.y += dy * dy;
    acc.z += dz * dz;
    acc.w += dw * dw;
  }
  *reinterpret_cast<float4*>(partial + (size_t)g * PIX + p) = acc;
}

// ---------------------------------------------------------------------------
// k1b: fold 16 slices -> diff2. 64 blocks x 64 threads; thread owns one
// float4 quad; 16 independent coalesced (1 KB/wave) loads, L2/L3-resident.
// ---------------------------------------------------------------------------
__global__ __launch_bounds__(64) void k_diff2_reduce(
    const float* __restrict__ partial, float* __restrict__ diff2) {
  int q = blockIdx.x * 64 + threadIdx.x;  // [0, 4096)
  int p = q << 2;
  float4 r = make_float4(0.f, 0.f, 0.f, 0.f);
#pragma unroll
  for (int g = 0; g < G; ++g) {
    float4 a = *reinterpret_cast<const float4*>(partial + (size_t)g * PIX + p);
    r.x += a.x;
    r.y += a.y;
    r.z += a.z;
    r.w += a.w;
  }
  *reinterpret_cast<float4*>(diff2 + p) = r;
}

// ---------------------------------------------------------------------------
// kB: one block per ROI; rectangle sum over diff2 (64 KB, cache-resident),
// atomicAdd of normalized MSE into out[0]. (R5/R6-proven, ~3 us.)
// ---------------------------------------------------------------------------
__global__ __launch_bounds__(256) void k_roi_mse(
    const float* __restrict__ diff2, const float* __restrict__ rois,
    const int* __restrict__ stride_p, float* __restrict__ out) {
  __shared__ float rsum[4];
  const int tid = threadIdx.x;
  const int bid = blockIdx.x;
  const int lane = tid & 63;
  const int w = tid >> 6;

  const float* r = rois + (size_t)bid * 5;
  const float inv_stride = 1.0f / (float)stride_p[0];
  int x1 = (int)floorf(r[1] * inv_stride);
  int y1 = (int)floorf(r[2] * inv_stride);
  int x2 = (int)floorf(r[3] * inv_stride);
  int y2 = (int)floorf(r[4] * inv_stride);
  if (!((y2 > y1) && (x2 > x1))) return;  // invalid ROI contributes 0

  const int rb = bid >> 8;  // ROI's batch
  const float* d2 = diff2 + (size_t)rb * HWv;
  float a2 = 0.f;
  for (int yy = y1 + w; yy <= y2; yy += 4)        // rows across waves
    for (int xx = x1 + lane; xx <= x2; xx += 64)  // cols across lanes
      a2 += d2[yy * Wv + xx];
#pragma unroll
  for (int off = 32; off > 0; off >>= 1) a2 += __shfl_down(a2, off, 64);
  if (lane == 0) rsum[w] = a2;
  __syncthreads();
  if (tid == 0) {
    float sse = rsum[0] + rsum[1] + rsum[2] + rsum[3];
    int area = (y2 - y1 + 1) * (x2 - x1 + 1);
    float mse = sse / ((float)Cv * (float)area);
    atomicAdd(out, mse * (1.0f / (float)(Bv * NROIS)));
  }
}

extern "C" void kernel_launch(void* const* d_in, const int* in_sizes, int n_in,
                              void* d_out, int out_size, void* d_ws,
                              size_t ws_size, hipStream_t stream) {
  const float* std_f = (const float*)d_in[0];
  const float* tch_f = (const float*)d_in[1];
  const float* rois = (const float*)d_in[2];
  const int* stride_p = (const int*)d_in[3];
  float* out = (float*)d_out;

  // ws layout: partial [G*PIX] | diff2 [PIX]
  float* partial = (float*)d_ws;            // 1 MB
  float* diff2 = partial + (size_t)G * PIX; // 64 KB

  k_diff2_partial<<<G * (PIX / 4) / 256, 256, 0, stream>>>(std_f, tch_f,
                                                           partial, out);
  k_diff2_reduce<<<PIX / 4 / 64, 64, 0, stream>>>(partial, diff2);
  k_roi_mse<<<Bv * NROIS, 256, 0, stream>>>(diff2, rois, stride_p, out);
}

// Round 8
// 32.691 us; speedup vs baseline: 1.2962x; 1.2962x over previous
//
#include <hip/hip_runtime.h>

// Problem constants (match reference)
constexpr int Bv = 4;
constexpr int Cv = 1024;
constexpr int Hv = 64;
constexpr int Wv = 64;
constexpr int NROIS = 256;
constexpr int HWv = Hv * Wv;   // 4096
constexpr int PIX = Bv * HWv;  // 16384
constexpr int G = 16;          // channel groups (R1-proven config)
constexpr int CPG = Cv / G;    // 64 channels per group

// ---------------------------------------------------------------------------
// k1 (R1-proven): thread t -> channel group g = t>>12, float4 pixel-quad
// v = t&4095. Each wave load = 1 KB contiguous (proven essential:
// 64B segs ~2.8 TB/s, 256B ~4.8 TB/s, 1KB ~5-6 TB/s effective).
// 256 blocks x 256 threads. NO atomics, no out[] touch.
// ---------------------------------------------------------------------------
__global__ __launch_bounds__(256) void k_diff2_partial(
    const float* __restrict__ std_f, const float* __restrict__ tch_f,
    float* __restrict__ partial) {
  int t = blockIdx.x * 256 + threadIdx.x;  // [0, 65536)
  int g = t >> 12;           // channel group [0,16)
  int v = t & 4095;          // float4-unit index over all pixels
  int p = v << 2;            // pixel index, 4 consecutive
  int b = p >> 12;           // batch (HW = 4096)
  int hw = p & 4095;         // pixel within batch

  const float* ps = std_f + ((size_t)b * Cv + (size_t)g * CPG) * HWv + hw;
  const float* pt = tch_f + ((size_t)b * Cv + (size_t)g * CPG) * HWv + hw;

  float4 acc = make_float4(0.f, 0.f, 0.f, 0.f);
#pragma unroll 4
  for (int c = 0; c < CPG; ++c) {
    float4 s = *reinterpret_cast<const float4*>(ps + (size_t)c * HWv);
    float4 q = *reinterpret_cast<const float4*>(pt + (size_t)c * HWv);
    float dx = s.x - q.x, dy = s.y - q.y, dz = s.z - q.z, dw = s.w - q.w;
    acc.x += dx * dx;
    acc.y += dy * dy;
    acc.z += dz * dz;
    acc.w += dw * dw;
  }
  *reinterpret_cast<float4*>(partial + (size_t)g * PIX + p) = acc;
}

// ---------------------------------------------------------------------------
// k1b (R1-proven): reduce 16 slices -> diff2. 64 blocks x 256 threads.
// ---------------------------------------------------------------------------
__global__ __launch_bounds__(256) void k_diff2_reduce(
    const float* __restrict__ partial, float* __restrict__ diff2) {
  int p = blockIdx.x * 256 + threadIdx.x;  // [0, 16384)
  float acc = 0.f;
#pragma unroll
  for (int g = 0; g < G; ++g) acc += partial[(size_t)g * PIX + p];
  diff2[p] = acc;
}

// ---------------------------------------------------------------------------
// k2: one block per ROI; stride-walk rectangle sum (no div/mod) over diff2
// (64 KB, cache-resident). PLAIN store of per-ROI mse; 0 for invalid.
// No atomics (R7 lesson: 1024 same-address atomicAdds cost ~10 us).
// ---------------------------------------------------------------------------
__global__ __launch_bounds__(256) void k_roi_mse(
    const float* __restrict__ diff2, const float* __restrict__ rois,
    const int* __restrict__ stride_p, float* __restrict__ roi_out) {
  __shared__ float rsum[4];
  const int tid = threadIdx.x;
  const int bid = blockIdx.x;
  const int lane = tid & 63;
  const int w = tid >> 6;

  const float* r = rois + (size_t)bid * 5;
  const float inv_stride = 1.0f / (float)stride_p[0];
  int x1 = (int)floorf(r[1] * inv_stride);
  int y1 = (int)floorf(r[2] * inv_stride);
  int x2 = (int)floorf(r[3] * inv_stride);
  int y2 = (int)floorf(r[4] * inv_stride);

  if (!((y2 > y1) && (x2 > x1))) {
    if (tid == 0) roi_out[bid] = 0.f;  // must write: ws is poisoned 0xAA
    return;
  }

  const int rb = bid >> 8;  // ROI's batch
  const float* d2 = diff2 + (size_t)rb * HWv;
  float a2 = 0.f;
  for (int yy = y1 + w; yy <= y2; yy += 4)        // rows across waves
    for (int xx = x1 + lane; xx <= x2; xx += 64)  // cols across lanes
      a2 += d2[yy * Wv + xx];
#pragma unroll
  for (int off = 32; off > 0; off >>= 1) a2 += __shfl_down(a2, off, 64);
  if (lane == 0) rsum[w] = a2;
  __syncthreads();
  if (tid == 0) {
    float sse = rsum[0] + rsum[1] + rsum[2] + rsum[3];
    int area = (y2 - y1 + 1) * (x2 - x1 + 1);
    roi_out[bid] = sse / ((float)Cv * (float)area);
  }
}

// ---------------------------------------------------------------------------
// k3: final sum over B*NROIS roi_mse values -> out[0]. 1 block x 256.
// Plain overwrite of out[0]; no zeroing needed anywhere.
// ---------------------------------------------------------------------------
__global__ __launch_bounds__(256) void k_final(
    const float* __restrict__ roi_out, float* __restrict__ out) {
  float acc = 0.f;
#pragma unroll
  for (int i = 0; i < (Bv * NROIS) / 256; ++i)
    acc += roi_out[i * 256 + threadIdx.x];
#pragma unroll
  for (int off = 32; off > 0; off >>= 1) acc += __shfl_down(acc, off, 64);
  __shared__ float smem[4];
  int lane = threadIdx.x & 63;
  int wid = threadIdx.x >> 6;
  if (lane == 0) smem[wid] = acc;
  __syncthreads();
  if (threadIdx.x == 0) {
    float total = smem[0] + smem[1] + smem[2] + smem[3];
    out[0] = total / (float)(Bv * NROIS);
  }
}

extern "C" void kernel_launch(void* const* d_in, const int* in_sizes, int n_in,
                              void* d_out, int out_size, void* d_ws,
                              size_t ws_size, hipStream_t stream) {
  const float* std_f = (const float*)d_in[0];
  const float* tch_f = (const float*)d_in[1];
  const float* rois = (const float*)d_in[2];
  const int* stride_p = (const int*)d_in[3];
  float* out = (float*)d_out;

  // ws layout: partial [G*PIX] | diff2 [PIX] | roi_out [B*NROIS]
  float* partial = (float*)d_ws;             // 1 MB
  float* diff2 = partial + (size_t)G * PIX;  // 64 KB
  float* roi_out = diff2 + PIX;              // 4 KB

  k_diff2_partial<<<G * (PIX / 4) / 256, 256, 0, stream>>>(std_f, tch_f,
                                                           partial);
  k_diff2_reduce<<<PIX / 256, 256, 0, stream>>>(partial, diff2);
  k_roi_mse<<<Bv * NROIS, 256, 0, stream>>>(diff2, rois, stride_p, roi_out);
  k_final<<<1, 256, 0, stream>>>(roi_out, out);
}